// Round 7
// baseline (653.279 us; speedup 1.0000x reference)
//
#include <hip/hip_runtime.h>
#include <hip/hip_fp16.h>

#define NUM_USERS 100000
#define NUM_ITEMS 50000
#define NTOT (NUM_USERS + NUM_ITEMS)
#define EMBED_DIM 64
#define NNZ_E 4800000
#define NUM_LAYERS 3

#define ROWS_PER_BUCKET 256
#define NBUCK ((NTOT + ROWS_PER_BUCKET - 1) / ROWS_PER_BUCKET)   // 586
#define BCAP 8960                   // mean 8191 + 8.5 sigma
#define EDGES_PER_BLOCK 16384
#define DMASK 0x3FFFF               // 18 bits for dst (< 150000 < 2^18)

// ---------------- init: b0(fp16) = concat(user_emb, item_emb) ----------------
__global__ void __launch_bounds__(256)
k_init(const float* __restrict__ ue, const float* __restrict__ ie,
       __half* __restrict__ b0) {
    const long long total2 = (long long)NTOT * EMBED_DIM / 2;
    const long long u2 = (long long)NUM_USERS * EMBED_DIM / 2;
    const float2* ue2 = (const float2*)ue;
    const float2* ie2 = (const float2*)ie;
    __half2* b02 = (__half2*)b0;
    for (long long i = (long long)blockIdx.x * blockDim.x + threadIdx.x;
         i < total2; i += (long long)gridDim.x * blockDim.x) {
        float2 v = (i < u2) ? ue2[i] : ie2[i - u2];
        b02[i] = __floats2half2_rn(v.x, v.y);
    }
}

// ---------------- phase 1: coarse bucket scatter (block-aggregated) ----------
// Streaming reads are non-temporal so they don't evict the partially-filled
// write sectors from L2 (write-merge is the whole game here).
__global__ void __launch_bounds__(256)
k_bucket(const int* __restrict__ src, const int* __restrict__ dst,
         const float* __restrict__ val, int* __restrict__ cursor,
         int2* __restrict__ outA) {
    __shared__ int h[NBUCK];
    __shared__ int base[NBUCK];
    for (int i = threadIdx.x; i < NBUCK; i += 256) h[i] = 0;
    __syncthreads();
    long long e0 = (long long)blockIdx.x * EDGES_PER_BLOCK;
    int n = (int)(((long long)NNZ_E - e0) < EDGES_PER_BLOCK ? (NNZ_E - e0)
                                                            : EDGES_PER_BLOCK);
    for (int i = threadIdx.x; i < n; i += 256) {
        int s = __builtin_nontemporal_load(&src[e0 + i]);
        atomicAdd(&h[s >> 8], 1);
    }
    __syncthreads();
    for (int i = threadIdx.x; i < NBUCK; i += 256) {
        int c = h[i];
        base[i] = (c > 0) ? atomicAdd(&cursor[i], c) : 0;
        h[i] = 0;
    }
    __syncthreads();
    for (int i = threadIdx.x; i < n; i += 256) {
        int s = __builtin_nontemporal_load(&src[e0 + i]);
        int d = __builtin_nontemporal_load(&dst[e0 + i]);
        float v = __builtin_nontemporal_load(&val[e0 + i]);
        int b = s >> 8;
        int off = base[b] + atomicAdd(&h[b], 1);
        outA[(long long)b * BCAP + off] =
            make_int2(d | ((s & 255) << 18), __float_as_int(v));
    }
}

// ---------------- phase 2: per-bucket LDS counting sort -> row-grouped ------
__global__ void __launch_bounds__(256)
k_sortbucket(const int2* __restrict__ inAll, const int* __restrict__ cursor,
             int2* __restrict__ outB, int2* __restrict__ rp) {
    __shared__ int h[ROWS_PER_BUCKET];
    __shared__ int excl[ROWS_PER_BUCKET];
    __shared__ int cur[ROWS_PER_BUCKET];
    int b = blockIdx.x;
    int t = threadIdx.x;
    int cnt = cursor[b];
    const long long* in8 = (const long long*)(inAll + (long long)b * BCAP);
    h[t] = 0;
    __syncthreads();
    for (int i = t; i < cnt; i += 256) {
        long long raw = __builtin_nontemporal_load(&in8[i]);
        atomicAdd(&h[((int)raw >> 18) & 255], 1);
    }
    __syncthreads();
    int v = h[t];
    excl[t] = v;
    __syncthreads();
    for (int off = 1; off < 256; off <<= 1) {
        int x = (t >= off) ? excl[t - off] : 0;
        __syncthreads();
        excl[t] += x;
        __syncthreads();
    }
    int myExcl = excl[t] - v;
    cur[t] = myExcl;
    long long gb = (long long)b * BCAP;
    int row = b * ROWS_PER_BUCKET + t;
    if (row < NTOT) rp[row] = make_int2((int)(gb + myExcl), (int)(gb + myExcl + v));
    __syncthreads();
    for (int i = t; i < cnt; i += 256) {
        long long raw = __builtin_nontemporal_load(&in8[i]);
        int ex = (int)raw;
        int r = (ex >> 18) & 255;
        int slot = atomicAdd(&cur[r], 1);
        outB[gb + slot] = make_int2(ex, (int)(raw >> 32));
    }
}

// ---- CSR SpMM: one wave per row, half2 gather (32 lanes/row), 2 edges/instr --
// LAST layer fuses the final average: out = (ego0 + b1 + b2 + acc) / 4.
template <bool LAST>
__global__ void __launch_bounds__(256)
k_spmm_csr(const int2* __restrict__ edges, const int2* __restrict__ rp,
           const __half* __restrict__ x, __half* __restrict__ nxt,
           const float* __restrict__ ue, const float* __restrict__ ie,
           const __half* __restrict__ b1, const __half* __restrict__ b2,
           float* __restrict__ out) {
    int row = blockIdx.x * 4 + (threadIdx.x >> 6);
    int lane = threadIdx.x & 63;
    if (row >= NTOT) return;
    int2 be = rp[row];
    int beg = be.x;
    int end = be.y;
    int sub = lane >> 5;
    int l2 = lane & 31;
    const __half2* x2 = (const __half2*)x;   // row stride 32 half2
    const long long* e8 = (const long long*)edges;
    float accx = 0.f, accy = 0.f;
    int j = beg;
    for (; j + 16 <= end; j += 16) {
        long long e[8];
        __half2 xv[8];
#pragma unroll
        for (int k = 0; k < 8; ++k)
            e[k] = __builtin_nontemporal_load(&e8[j + sub * 8 + k]);
#pragma unroll
        for (int k = 0; k < 8; ++k)
            xv[k] = x2[(long long)((int)e[k] & DMASK) * 32 + l2];
#pragma unroll
        for (int k = 0; k < 8; ++k) {
            float w = __int_as_float((int)(e[k] >> 32));
            float2 xf = __half22float2(xv[k]);
            accx = fmaf(w, xf.x, accx);
            accy = fmaf(w, xf.y, accy);
        }
    }
    for (int t2 = j + sub; t2 < end; t2 += 2) {
        long long e = __builtin_nontemporal_load(&e8[t2]);
        float w = __int_as_float((int)(e >> 32));
        float2 xf = __half22float2(x2[(long long)((int)e & DMASK) * 32 + l2]);
        accx = fmaf(w, xf.x, accx);
        accy = fmaf(w, xf.y, accy);
    }
    accx += __shfl_xor(accx, 32);
    accy += __shfl_xor(accy, 32);
    if (sub == 0) {
        if (!LAST) {
            ((__half2*)nxt)[(long long)row * 32 + l2] = __floats2half2_rn(accx, accy);
        } else {
            const float2* ego2 = (row < NUM_USERS)
                ? (const float2*)(ue + (long long)row * EMBED_DIM)
                : (const float2*)(ie + (long long)(row - NUM_USERS) * EMBED_DIM);
            float2 v = ego2[l2];
            float2 a = __half22float2(((const __half2*)b1)[(long long)row * 32 + l2]);
            float2 bb = __half22float2(((const __half2*)b2)[(long long)row * 32 + l2]);
            const float s = 1.0f / (NUM_LAYERS + 1);
            float2 r;
            r.x = (v.x + a.x + bb.x + accx) * s;
            r.y = (v.y + a.y + bb.y + accy) * s;
            ((float2*)out)[(long long)row * 32 + l2] = r;
        }
    }
}

extern "C" void kernel_launch(void* const* d_in, const int* in_sizes, int n_in,
                              void* d_out, int out_size, void* d_ws, size_t ws_size,
                              hipStream_t stream) {
    const float* user_emb = (const float*)d_in[0];
    const float* item_emb = (const float*)d_in[1];
    const int* edge_src   = (const int*)d_in[2];
    const int* edge_dst   = (const int*)d_in[3];
    const float* edge_val = (const float*)d_in[4];
    float* out = (float*)d_out;

    // ---- workspace layout ----
    // [0 .. 57.6MB) : b0,b1,b2 (3 x 19.2MB fp16). bucketedA (42MB) ALIASES this
    //                 region; dead before k_init writes b0.
    // then bucketedB (42MB, live all layers), rp (int2), cursor.
    char* p = (char*)d_ws;
    const size_t halfMat = (size_t)NTOT * EMBED_DIM * sizeof(__half);   // 19.2 MB
    const size_t buckBytes = (size_t)NBUCK * BCAP * sizeof(int2);       // 42.0 MB
    __half* b0 = (__half*)p;                 p += halfMat;
    __half* b1 = (__half*)p;                 p += halfMat;
    __half* b2 = (__half*)p;                 p += halfMat;
    int2* bucketedA = (int2*)d_ws;           // alias of b0..b2 region
    int2* bucketedB = (int2*)p;              p += buckBytes;
    int2* rp = (int2*)p;                     p += ((size_t)NTOT + 8) * sizeof(int2);
    int* cursor = (int*)p;                   p += (size_t)NBUCK * sizeof(int);

    // 1. coarse bucket scatter
    hipMemsetAsync(cursor, 0, (size_t)NBUCK * sizeof(int), stream);
    const int bucketBlocks = (NNZ_E + EDGES_PER_BLOCK - 1) / EDGES_PER_BLOCK;  // 293
    hipLaunchKernelGGL(k_bucket, dim3(bucketBlocks), dim3(256), 0, stream,
                       edge_src, edge_dst, edge_val, cursor, bucketedA);

    // 2. per-bucket counting sort -> bucketedB + packed row ptrs
    hipLaunchKernelGGL(k_sortbucket, dim3(NBUCK), dim3(256), 0, stream,
                       bucketedA, cursor, bucketedB, rp);

    // 3. init b0 (fp16 ego), overwrites bucketedA region
    hipLaunchKernelGGL(k_init, dim3(2048), dim3(256), 0, stream,
                       user_emb, item_emb, b0);

    // 4. layers 1..2 write fp16 buffers; layer 3 fuses the final average
    const int spmmBlocks = (NTOT + 3) / 4;
    hipLaunchKernelGGL((k_spmm_csr<false>), dim3(spmmBlocks), dim3(256), 0, stream,
                       bucketedB, rp, b0, b1, user_emb, item_emb,
                       (const __half*)nullptr, (const __half*)nullptr, out);
    hipLaunchKernelGGL((k_spmm_csr<false>), dim3(spmmBlocks), dim3(256), 0, stream,
                       bucketedB, rp, b1, b2, user_emb, item_emb,
                       (const __half*)nullptr, (const __half*)nullptr, out);
    hipLaunchKernelGGL((k_spmm_csr<true>), dim3(spmmBlocks), dim3(256), 0, stream,
                       bucketedB, rp, b2, (__half*)nullptr, user_emb, item_emb,
                       b1, b2, out);
}

// Round 8
// 571.929 us; speedup vs baseline: 1.1422x; 1.1422x over previous
//
#include <hip/hip_runtime.h>
#include <hip/hip_fp16.h>

#define NUM_USERS 100000
#define NUM_ITEMS 50000
#define NTOT (NUM_USERS + NUM_ITEMS)
#define EMBED_DIM 64
#define NNZ_E 4800000
#define NUM_LAYERS 3

#define ROWS_PER_BUCKET 256
#define NBUCK ((NTOT + ROWS_PER_BUCKET - 1) / ROWS_PER_BUCKET)   // 586
#define BCAP 8960                   // mean 8191 + 8.5 sigma
#define EDGES_PER_BLOCK 16384
#define DMASK 0x3FFFF               // 18 bits for dst (< 150000 < 2^18)

// ---------------- init: b0(fp16) = concat(user_emb, item_emb) ----------------
__global__ void __launch_bounds__(256)
k_init(const float* __restrict__ ue, const float* __restrict__ ie,
       __half* __restrict__ b0) {
    const long long total2 = (long long)NTOT * EMBED_DIM / 2;
    const long long u2 = (long long)NUM_USERS * EMBED_DIM / 2;
    const float2* ue2 = (const float2*)ue;
    const float2* ie2 = (const float2*)ie;
    __half2* b02 = (__half2*)b0;
    for (long long i = (long long)blockIdx.x * blockDim.x + threadIdx.x;
         i < total2; i += (long long)gridDim.x * blockDim.x) {
        float2 v = (i < u2) ? ue2[i] : ie2[i - u2];
        b02[i] = __floats2half2_rn(v.x, v.y);
    }
}

// ---------------- phase 1: coarse bucket scatter (block-aggregated) ----------
// NT reads here are genuinely single-touch streams.
__global__ void __launch_bounds__(256)
k_bucket(const int* __restrict__ src, const int* __restrict__ dst,
         const float* __restrict__ val, int* __restrict__ cursor,
         int2* __restrict__ outA) {
    __shared__ int h[NBUCK];
    __shared__ int base[NBUCK];
    for (int i = threadIdx.x; i < NBUCK; i += 256) h[i] = 0;
    __syncthreads();
    long long e0 = (long long)blockIdx.x * EDGES_PER_BLOCK;
    int n = (int)(((long long)NNZ_E - e0) < EDGES_PER_BLOCK ? (NNZ_E - e0)
                                                            : EDGES_PER_BLOCK);
    for (int i = threadIdx.x; i < n; i += 256) {
        int s = __builtin_nontemporal_load(&src[e0 + i]);
        atomicAdd(&h[s >> 8], 1);
    }
    __syncthreads();
    for (int i = threadIdx.x; i < NBUCK; i += 256) {
        int c = h[i];
        base[i] = (c > 0) ? atomicAdd(&cursor[i], c) : 0;
        h[i] = 0;
    }
    __syncthreads();
    for (int i = threadIdx.x; i < n; i += 256) {
        int s = __builtin_nontemporal_load(&src[e0 + i]);
        int d = __builtin_nontemporal_load(&dst[e0 + i]);
        float v = __builtin_nontemporal_load(&val[e0 + i]);
        int b = s >> 8;
        int off = base[b] + atomicAdd(&h[b], 1);
        outA[(long long)b * BCAP + off] =
            make_int2(d | ((s & 255) << 18), __float_as_int(v));
    }
}

// ---------------- phase 2: per-bucket LDS counting sort -> row-grouped ------
__global__ void __launch_bounds__(256)
k_sortbucket(const int2* __restrict__ inAll, const int* __restrict__ cursor,
             int2* __restrict__ outB, int2* __restrict__ rp) {
    __shared__ int h[ROWS_PER_BUCKET];
    __shared__ int excl[ROWS_PER_BUCKET];
    __shared__ int cur[ROWS_PER_BUCKET];
    int b = blockIdx.x;
    int t = threadIdx.x;
    int cnt = cursor[b];
    const long long* in8 = (const long long*)(inAll + (long long)b * BCAP);
    h[t] = 0;
    __syncthreads();
    for (int i = t; i < cnt; i += 256) {
        long long raw = __builtin_nontemporal_load(&in8[i]);
        atomicAdd(&h[((int)raw >> 18) & 255], 1);
    }
    __syncthreads();
    int v = h[t];
    excl[t] = v;
    __syncthreads();
    for (int off = 1; off < 256; off <<= 1) {
        int x = (t >= off) ? excl[t - off] : 0;
        __syncthreads();
        excl[t] += x;
        __syncthreads();
    }
    int myExcl = excl[t] - v;
    cur[t] = myExcl;
    long long gb = (long long)b * BCAP;
    int row = b * ROWS_PER_BUCKET + t;
    if (row < NTOT) rp[row] = make_int2((int)(gb + myExcl), (int)(gb + myExcl + v));
    __syncthreads();
    for (int i = t; i < cnt; i += 256) {
        long long raw = __builtin_nontemporal_load(&in8[i]);
        int ex = (int)raw;
        int r = (ex >> 18) & 255;
        int slot = atomicAdd(&cur[r], 1);
        outB[gb + slot] = make_int2(ex, (int)(raw >> 32));
    }
}

// ---- CSR SpMM: one wave per row, half2 gather (32 lanes/row), 2 edges/instr --
// Edge descriptors: cached (L1-hit broadcast) loads, double-buffered so the
// next group's loads overlap the current group's gathers.
// LAST layer fuses the final average: out = (ego0 + b1 + b2 + acc) / 4.
template <bool LAST>
__global__ void __launch_bounds__(256)
k_spmm_csr(const int2* __restrict__ edges, const int2* __restrict__ rp,
           const __half* __restrict__ x, __half* __restrict__ nxt,
           const float* __restrict__ ue, const float* __restrict__ ie,
           const __half* __restrict__ b1, const __half* __restrict__ b2,
           float* __restrict__ out) {
    int row = blockIdx.x * 4 + (threadIdx.x >> 6);
    int lane = threadIdx.x & 63;
    if (row >= NTOT) return;
    int2 be = rp[row];
    int beg = be.x;
    int end = be.y;
    int sub = lane >> 5;
    int l2 = lane & 31;
    const __half2* x2 = (const __half2*)x;   // row stride 32 half2
    const long long* e8 = (const long long*)edges;
    float accx = 0.f, accy = 0.f;

    int j = beg;
    long long eA[8];
    if (j + 16 <= end) {
#pragma unroll
        for (int k = 0; k < 8; ++k) eA[k] = e8[j + sub * 8 + k];
    }
    for (; j + 16 <= end;) {
        int jn = j + 16;
        long long eB[8];
        if (jn + 16 <= end) {
#pragma unroll
            for (int k = 0; k < 8; ++k) eB[k] = e8[jn + sub * 8 + k];
        }
        __half2 xv[8];
#pragma unroll
        for (int k = 0; k < 8; ++k)
            xv[k] = x2[(long long)((int)eA[k] & DMASK) * 32 + l2];
#pragma unroll
        for (int k = 0; k < 8; ++k) {
            float w = __int_as_float((int)(eA[k] >> 32));
            float2 xf = __half22float2(xv[k]);
            accx = fmaf(w, xf.x, accx);
            accy = fmaf(w, xf.y, accy);
        }
#pragma unroll
        for (int k = 0; k < 8; ++k) eA[k] = eB[k];
        j = jn;
    }
    for (int t2 = j + sub; t2 < end; t2 += 2) {
        long long e = e8[t2];
        float w = __int_as_float((int)(e >> 32));
        float2 xf = __half22float2(x2[(long long)((int)e & DMASK) * 32 + l2]);
        accx = fmaf(w, xf.x, accx);
        accy = fmaf(w, xf.y, accy);
    }
    accx += __shfl_xor(accx, 32);
    accy += __shfl_xor(accy, 32);
    if (sub == 0) {
        if (!LAST) {
            ((__half2*)nxt)[(long long)row * 32 + l2] = __floats2half2_rn(accx, accy);
        } else {
            const float2* ego2 = (row < NUM_USERS)
                ? (const float2*)(ue + (long long)row * EMBED_DIM)
                : (const float2*)(ie + (long long)(row - NUM_USERS) * EMBED_DIM);
            float2 v = ego2[l2];
            float2 a = __half22float2(((const __half2*)b1)[(long long)row * 32 + l2]);
            float2 bb = __half22float2(((const __half2*)b2)[(long long)row * 32 + l2]);
            const float s = 1.0f / (NUM_LAYERS + 1);
            float2 r;
            r.x = (v.x + a.x + bb.x + accx) * s;
            r.y = (v.y + a.y + bb.y + accy) * s;
            ((float2*)out)[(long long)row * 32 + l2] = r;
        }
    }
}

extern "C" void kernel_launch(void* const* d_in, const int* in_sizes, int n_in,
                              void* d_out, int out_size, void* d_ws, size_t ws_size,
                              hipStream_t stream) {
    const float* user_emb = (const float*)d_in[0];
    const float* item_emb = (const float*)d_in[1];
    const int* edge_src   = (const int*)d_in[2];
    const int* edge_dst   = (const int*)d_in[3];
    const float* edge_val = (const float*)d_in[4];
    float* out = (float*)d_out;

    // ---- workspace layout ----
    char* p = (char*)d_ws;
    const size_t halfMat = (size_t)NTOT * EMBED_DIM * sizeof(__half);   // 19.2 MB
    const size_t buckBytes = (size_t)NBUCK * BCAP * sizeof(int2);       // 42.0 MB
    __half* b0 = (__half*)p;                 p += halfMat;
    __half* b1 = (__half*)p;                 p += halfMat;
    __half* b2 = (__half*)p;                 p += halfMat;
    int2* bucketedA = (int2*)d_ws;           // alias of b0..b2 region (dead before k_init)
    int2* bucketedB = (int2*)p;              p += buckBytes;
    int2* rp = (int2*)p;                     p += ((size_t)NTOT + 8) * sizeof(int2);
    int* cursor = (int*)p;                   p += (size_t)NBUCK * sizeof(int);

    // 1. coarse bucket scatter
    hipMemsetAsync(cursor, 0, (size_t)NBUCK * sizeof(int), stream);
    const int bucketBlocks = (NNZ_E + EDGES_PER_BLOCK - 1) / EDGES_PER_BLOCK;  // 293
    hipLaunchKernelGGL(k_bucket, dim3(bucketBlocks), dim3(256), 0, stream,
                       edge_src, edge_dst, edge_val, cursor, bucketedA);

    // 2. per-bucket counting sort -> bucketedB + packed row ptrs
    hipLaunchKernelGGL(k_sortbucket, dim3(NBUCK), dim3(256), 0, stream,
                       bucketedA, cursor, bucketedB, rp);

    // 3. init b0 (fp16 ego), overwrites bucketedA region
    hipLaunchKernelGGL(k_init, dim3(2048), dim3(256), 0, stream,
                       user_emb, item_emb, b0);

    // 4. layers 1..2 write fp16 buffers; layer 3 fuses the final average
    const int spmmBlocks = (NTOT + 3) / 4;
    hipLaunchKernelGGL((k_spmm_csr<false>), dim3(spmmBlocks), dim3(256), 0, stream,
                       bucketedB, rp, b0, b1, user_emb, item_emb,
                       (const __half*)nullptr, (const __half*)nullptr, out);
    hipLaunchKernelGGL((k_spmm_csr<false>), dim3(spmmBlocks), dim3(256), 0, stream,
                       bucketedB, rp, b1, b2, user_emb, item_emb,
                       (const __half*)nullptr, (const __half*)nullptr, out);
    hipLaunchKernelGGL((k_spmm_csr<true>), dim3(spmmBlocks), dim3(256), 0, stream,
                       bucketedB, rp, b2, (__half*)nullptr, user_emb, item_emb,
                       b1, b2, out);
}

// Round 9
// 520.190 us; speedup vs baseline: 1.2558x; 1.0995x over previous
//
#include <hip/hip_runtime.h>
#include <hip/hip_fp16.h>

#define NUM_USERS 100000
#define NUM_ITEMS 50000
#define NTOT (NUM_USERS + NUM_ITEMS)
#define EMBED_DIM 64
#define NNZ_E 4800000
#define NUM_LAYERS 3

#define ROWS_PER_BUCKET 256
#define NBUCK ((NTOT + ROWS_PER_BUCKET - 1) / ROWS_PER_BUCKET)   // 586
#define BCAP 8960                   // mean 8191 + 8.5 sigma
#define EDGES_PER_BLOCK 4096        // 1172 blocks -> ~4.6 blocks/CU (occupancy fix)
#define DMASK 0x3FFFF               // 18 bits for dst (< 150000 < 2^18)

// ---------------- init: b0(fp16) = concat(user_emb, item_emb) ----------------
__global__ void __launch_bounds__(256)
k_init(const float* __restrict__ ue, const float* __restrict__ ie,
       __half* __restrict__ b0) {
    const long long total2 = (long long)NTOT * EMBED_DIM / 2;
    const long long u2 = (long long)NUM_USERS * EMBED_DIM / 2;
    const float2* ue2 = (const float2*)ue;
    const float2* ie2 = (const float2*)ie;
    __half2* b02 = (__half2*)b0;
    for (long long i = (long long)blockIdx.x * blockDim.x + threadIdx.x;
         i < total2; i += (long long)gridDim.x * blockDim.x) {
        float2 v = (i < u2) ? ue2[i] : ie2[i - u2];
        b02[i] = __floats2half2_rn(v.x, v.y);
    }
}

// ---------------- phase 1: coarse bucket scatter (block-aggregated) ----------
__global__ void __launch_bounds__(256)
k_bucket(const int* __restrict__ src, const int* __restrict__ dst,
         const float* __restrict__ val, int* __restrict__ cursor,
         int2* __restrict__ outA) {
    __shared__ int h[NBUCK];
    __shared__ int base[NBUCK];
    for (int i = threadIdx.x; i < NBUCK; i += 256) h[i] = 0;
    __syncthreads();
    long long e0 = (long long)blockIdx.x * EDGES_PER_BLOCK;
    int n = (int)(((long long)NNZ_E - e0) < EDGES_PER_BLOCK ? (NNZ_E - e0)
                                                            : EDGES_PER_BLOCK);
    for (int i = threadIdx.x; i < n; i += 256) {
        int s = __builtin_nontemporal_load(&src[e0 + i]);
        atomicAdd(&h[s >> 8], 1);
    }
    __syncthreads();
    for (int i = threadIdx.x; i < NBUCK; i += 256) {
        int c = h[i];
        base[i] = (c > 0) ? atomicAdd(&cursor[i], c) : 0;
        h[i] = 0;
    }
    __syncthreads();
    for (int i = threadIdx.x; i < n; i += 256) {
        int s = __builtin_nontemporal_load(&src[e0 + i]);
        int d = __builtin_nontemporal_load(&dst[e0 + i]);
        float v = __builtin_nontemporal_load(&val[e0 + i]);
        int b = s >> 8;
        int off = base[b] + atomicAdd(&h[b], 1);
        outA[(long long)b * BCAP + off] =
            make_int2(d | ((s & 255) << 18), __float_as_int(v));
    }
}

// ---------------- phase 2: per-bucket LDS counting sort -> row-grouped ------
__global__ void __launch_bounds__(256)
k_sortbucket(const int2* __restrict__ inAll, const int* __restrict__ cursor,
             int2* __restrict__ outB, int2* __restrict__ rp) {
    __shared__ int h[ROWS_PER_BUCKET];
    __shared__ int excl[ROWS_PER_BUCKET];
    __shared__ int cur[ROWS_PER_BUCKET];
    int b = blockIdx.x;
    int t = threadIdx.x;
    int cnt = cursor[b];
    const long long* in8 = (const long long*)(inAll + (long long)b * BCAP);
    h[t] = 0;
    __syncthreads();
    for (int i = t; i < cnt; i += 256) {
        long long raw = __builtin_nontemporal_load(&in8[i]);
        atomicAdd(&h[((int)raw >> 18) & 255], 1);
    }
    __syncthreads();
    int v = h[t];
    excl[t] = v;
    __syncthreads();
    for (int off = 1; off < 256; off <<= 1) {
        int x = (t >= off) ? excl[t - off] : 0;
        __syncthreads();
        excl[t] += x;
        __syncthreads();
    }
    int myExcl = excl[t] - v;
    cur[t] = myExcl;
    long long gb = (long long)b * BCAP;
    int row = b * ROWS_PER_BUCKET + t;
    if (row < NTOT) rp[row] = make_int2((int)(gb + myExcl), (int)(gb + myExcl + v));
    __syncthreads();
    for (int i = t; i < cnt; i += 256) {
        long long raw = __builtin_nontemporal_load(&in8[i]);
        int ex = (int)raw;
        int r = (ex >> 18) & 255;
        int slot = atomicAdd(&cur[r], 1);
        outB[gb + slot] = make_int2(ex, (int)(raw >> 32));
    }
}

// ---- gather group: 2*U edges at j; half-wave `sub` handles U of them ----
template <int U>
__device__ __forceinline__ void gather_group(const long long* __restrict__ e8,
                                             int j, int sub, int l2,
                                             const __half2* __restrict__ x2,
                                             float& accx, float& accy) {
    long long e[U];
    __half2 xv[U];
#pragma unroll
    for (int k = 0; k < U; ++k) e[k] = e8[j + sub * U + k];
#pragma unroll
    for (int k = 0; k < U; ++k)
        xv[k] = x2[(long long)((int)e[k] & DMASK) * 32 + l2];
#pragma unroll
    for (int k = 0; k < U; ++k) {
        float w = __int_as_float((int)(e[k] >> 32));
        float2 xf = __half22float2(xv[k]);
        accx = fmaf(w, xf.x, accx);
        accy = fmaf(w, xf.y, accy);
    }
}

// ---- CSR SpMM: one wave per row, half2 gather (32 lanes/row) ---------------
// Tiered unroll 16/8/4 + alternating scalar tail (<=7 edges).
// LAST layer fuses the final average: out = (ego0 + b1 + b2 + acc) / 4.
template <bool LAST>
__global__ void __launch_bounds__(256)
k_spmm_csr(const int2* __restrict__ edges, const int2* __restrict__ rp,
           const __half* __restrict__ x, __half* __restrict__ nxt,
           const float* __restrict__ ue, const float* __restrict__ ie,
           const __half* __restrict__ b1, const __half* __restrict__ b2,
           float* __restrict__ out) {
    int row = blockIdx.x * 4 + (threadIdx.x >> 6);
    int lane = threadIdx.x & 63;
    if (row >= NTOT) return;
    int2 be = rp[row];
    int beg = be.x;
    int end = be.y;
    int sub = lane >> 5;
    int l2 = lane & 31;
    const __half2* x2 = (const __half2*)x;   // row stride 32 half2
    const long long* e8 = (const long long*)edges;
    float accx = 0.f, accy = 0.f;

    int j = beg;
    while (j + 32 <= end) { gather_group<16>(e8, j, sub, l2, x2, accx, accy); j += 32; }
    if (j + 16 <= end)    { gather_group<8>(e8, j, sub, l2, x2, accx, accy);  j += 16; }
    if (j + 8 <= end)     { gather_group<4>(e8, j, sub, l2, x2, accx, accy);  j += 8; }
    for (int t2 = j + sub; t2 < end; t2 += 2) {
        long long e = e8[t2];
        float w = __int_as_float((int)(e >> 32));
        float2 xf = __half22float2(x2[(long long)((int)e & DMASK) * 32 + l2]);
        accx = fmaf(w, xf.x, accx);
        accy = fmaf(w, xf.y, accy);
    }
    accx += __shfl_xor(accx, 32);
    accy += __shfl_xor(accy, 32);
    if (sub == 0) {
        if (!LAST) {
            ((__half2*)nxt)[(long long)row * 32 + l2] = __floats2half2_rn(accx, accy);
        } else {
            const float2* ego2 = (row < NUM_USERS)
                ? (const float2*)(ue + (long long)row * EMBED_DIM)
                : (const float2*)(ie + (long long)(row - NUM_USERS) * EMBED_DIM);
            float2 v = ego2[l2];
            float2 a = __half22float2(((const __half2*)b1)[(long long)row * 32 + l2]);
            float2 bb = __half22float2(((const __half2*)b2)[(long long)row * 32 + l2]);
            const float s = 1.0f / (NUM_LAYERS + 1);
            float2 r;
            r.x = (v.x + a.x + bb.x + accx) * s;
            r.y = (v.y + a.y + bb.y + accy) * s;
            ((float2*)out)[(long long)row * 32 + l2] = r;
        }
    }
}

extern "C" void kernel_launch(void* const* d_in, const int* in_sizes, int n_in,
                              void* d_out, int out_size, void* d_ws, size_t ws_size,
                              hipStream_t stream) {
    const float* user_emb = (const float*)d_in[0];
    const float* item_emb = (const float*)d_in[1];
    const int* edge_src   = (const int*)d_in[2];
    const int* edge_dst   = (const int*)d_in[3];
    const float* edge_val = (const float*)d_in[4];
    float* out = (float*)d_out;

    // ---- workspace layout ----
    char* p = (char*)d_ws;
    const size_t halfMat = (size_t)NTOT * EMBED_DIM * sizeof(__half);   // 19.2 MB
    const size_t buckBytes = (size_t)NBUCK * BCAP * sizeof(int2);       // 42.0 MB
    __half* b0 = (__half*)p;                 p += halfMat;
    __half* b1 = (__half*)p;                 p += halfMat;
    __half* b2 = (__half*)p;                 p += halfMat;
    int2* bucketedA = (int2*)d_ws;           // alias of b0..b2 region (dead before k_init)
    int2* bucketedB = (int2*)p;              p += buckBytes;
    int2* rp = (int2*)p;                     p += ((size_t)NTOT + 8) * sizeof(int2);
    int* cursor = (int*)p;                   p += (size_t)NBUCK * sizeof(int);

    // 1. coarse bucket scatter
    hipMemsetAsync(cursor, 0, (size_t)NBUCK * sizeof(int), stream);
    const int bucketBlocks = (NNZ_E + EDGES_PER_BLOCK - 1) / EDGES_PER_BLOCK;  // 1172
    hipLaunchKernelGGL(k_bucket, dim3(bucketBlocks), dim3(256), 0, stream,
                       edge_src, edge_dst, edge_val, cursor, bucketedA);

    // 2. per-bucket counting sort -> bucketedB + packed row ptrs
    hipLaunchKernelGGL(k_sortbucket, dim3(NBUCK), dim3(256), 0, stream,
                       bucketedA, cursor, bucketedB, rp);

    // 3. init b0 (fp16 ego), overwrites bucketedA region
    hipLaunchKernelGGL(k_init, dim3(2048), dim3(256), 0, stream,
                       user_emb, item_emb, b0);

    // 4. layers 1..2 write fp16 buffers; layer 3 fuses the final average
    const int spmmBlocks = (NTOT + 3) / 4;
    hipLaunchKernelGGL((k_spmm_csr<false>), dim3(spmmBlocks), dim3(256), 0, stream,
                       bucketedB, rp, b0, b1, user_emb, item_emb,
                       (const __half*)nullptr, (const __half*)nullptr, out);
    hipLaunchKernelGGL((k_spmm_csr<false>), dim3(spmmBlocks), dim3(256), 0, stream,
                       bucketedB, rp, b1, b2, user_emb, item_emb,
                       (const __half*)nullptr, (const __half*)nullptr, out);
    hipLaunchKernelGGL((k_spmm_csr<true>), dim3(spmmBlocks), dim3(256), 0, stream,
                       bucketedB, rp, b2, (__half*)nullptr, user_emb, item_emb,
                       b1, b2, out);
}